// Round 5
// baseline (526.879 us; speedup 1.0000x reference)
//
#include <hip/hip_runtime.h>

typedef __bf16 bf16;
typedef __bf16 bf16x8 __attribute__((ext_vector_type(8)));
typedef float  f32x4  __attribute__((ext_vector_type(4)));

#define HALF   4096
#define S_TOT  8192
#define HID    2048
#define NH     16
#define NKV    4
#define DH     128
#define LSEQ   512

typedef const __attribute__((address_space(1))) void* as1_cvp;
typedef __attribute__((address_space(3))) void* as3_vp;

__device__ __forceinline__ void gl2lds16(const void* g, void* l) {
    // HW semantics: lane i's 16B lands at (wave-uniform) l + i*16
    __builtin_amdgcn_global_load_lds((as1_cvp)g, (as3_vp)l, 16, 0, 0);
}

#define VMCNT(n) asm volatile("s_waitcnt vmcnt(" #n ")" ::: "memory")

__device__ __forceinline__ float bfu_lo(unsigned u) { return __uint_as_float(u << 16); }
__device__ __forceinline__ float bfu_hi(unsigned u) { return __uint_as_float(u & 0xffff0000u); }

// ---------------- fp32 -> bf16 convert (+ invtyp tail blocks) --------------------
// Segment sizes compile-time (fl4/256 blocks): xu 8192, xg 8192, qw 4096, kw 1024,
// vw 1024, qwg 4096, kwg 1024, vwg 1024, ow 4096, owg 4096 = 36864; +16 invtyp.
struct CvtArgs {
    const float* src[10];
    bf16*        dst[10];
    int          n4[10];
};
__global__ __launch_bounds__(256) void k_convert_seg(CvtArgs a,
    const int* __restrict__ ui, const int* __restrict__ gi, int* __restrict__ it) {
    int rem = blockIdx.x;
    if (rem >= 36864) {            // invtyp tail: invtyp[s] = packed_row*2 | is_gen
        int t = (rem - 36864) * 256 + threadIdx.x;
        if (t < HALF) { it[ui[t]] = t << 1; it[gi[t]] = (t << 1) | 1; }
        return;
    }
    const float* src; bf16* dst;
    if      (rem < 8192)           { src=a.src[0]; dst=a.dst[0]; }
    else if ((rem -= 8192) < 8192) { src=a.src[1]; dst=a.dst[1]; }
    else if ((rem -= 8192) < 4096) { src=a.src[2]; dst=a.dst[2]; }
    else if ((rem -= 4096) < 1024) { src=a.src[3]; dst=a.dst[3]; }
    else if ((rem -= 1024) < 1024) { src=a.src[4]; dst=a.dst[4]; }
    else if ((rem -= 1024) < 4096) { src=a.src[5]; dst=a.dst[5]; }
    else if ((rem -= 4096) < 1024) { src=a.src[6]; dst=a.dst[6]; }
    else if ((rem -= 1024) < 1024) { src=a.src[7]; dst=a.dst[7]; }
    else if ((rem -= 1024) < 4096) { src=a.src[8]; dst=a.dst[8]; }
    else    { rem -= 4096;           src=a.src[9]; dst=a.dst[9]; }
    const int i = (rem << 8) + threadIdx.x;
    float4 v = ((const float4*)src)[i];
    union { bf16 b[4]; ushort4 u; } t;
    t.b[0] = (bf16)v.x; t.b[1] = (bf16)v.y; t.b[2] = (bf16)v.z; t.b[3] = (bf16)v.w;
    ((ushort4*)dst)[i] = t.u;
}

// ---------------- QKV GEMM (128^2/BK32 R0 core) + FUSED RMSNorm+RoPE epilogue ----
// n-tile width 128 == head dim -> each block's output tile holds complete heads.
// Block-uniform: nb<16 Q-head, nb<20 K-head (norm+rope fused), else V (plain).
// Q rows scaled by 1/sqrt(D)*log2(e) so attention softmax is pure exp2.
__global__ __launch_bounds__(256) void k_gemm_qkv(
    const bf16* __restrict__ Xu, const bf16* __restrict__ Xg,
    const bf16* __restrict__ Wu, const bf16* __restrict__ Wg,
    const float* __restrict__ qbu, const float* __restrict__ kbu, const float* __restrict__ vbu,
    const float* __restrict__ qbg, const float* __restrict__ kbg, const float* __restrict__ vbg,
    const int* __restrict__ ui, const int* __restrict__ gi,
    const float* __restrict__ qnu, const float* __restrict__ qng,
    const float* __restrict__ knu, const float* __restrict__ kng,
    const float* __restrict__ cosb, const float* __restrict__ sinb,
    bf16* __restrict__ qo, bf16* __restrict__ ko, bf16* __restrict__ vo)
{
    const int gen = blockIdx.z;
    const bf16* X = gen ? Xg : Xu;
    const bf16* W = gen ? Wg : Wu;
    const float* qb = gen ? qbg : qbu;
    const float* kb = gen ? kbg : kbu;
    const float* vb = gen ? vbg : vbu;
    const int* idx = gen ? gi : ui;

    __shared__ __align__(16) bf16 sA[128*32];
    __shared__ __align__(16) bf16 sB[128*32];
    __shared__ __align__(8)  bf16 sX[128*132];   // epilogue x tile, stride-132 rows

    const int tid = threadIdx.x;
    const int wave = tid >> 6, lane = tid & 63;
    const int lm = lane & 15, kq = lane >> 4;
    const int wm = wave >> 1, wn = wave & 1;
    const int m0 = blockIdx.y * 128, n0 = blockIdx.x * 128;

    f32x4 acc[4][4] = {};

    for (int k0 = 0; k0 < HID; k0 += 32) {
        __syncthreads();
        #pragma unroll
        for (int i = 0; i < 2; ++i) {
            const int g = i*4 + wave;
            const int c = g*64 + lane;
            const int row = c >> 2, col = c & 3;
            gl2lds16(X + (size_t)(m0+row)*HID + k0 + col*8, (char*)sA + (size_t)g*1024);
            gl2lds16(W + (size_t)(n0+row)*HID + k0 + col*8, (char*)sB + (size_t)g*1024);
        }
        __syncthreads();
        bf16x8 a[4], b[4];
        #pragma unroll
        for (int i = 0; i < 4; ++i) a[i] = *(const bf16x8*)&sA[(wm*64 + i*16 + lm)*32 + kq*8];
        #pragma unroll
        for (int j = 0; j < 4; ++j) b[j] = *(const bf16x8*)&sB[(wn*64 + j*16 + lm)*32 + kq*8];
        #pragma unroll
        for (int i = 0; i < 4; ++i)
            #pragma unroll
            for (int j = 0; j < 4; ++j)
                acc[i][j] = __builtin_amdgcn_mfma_f32_16x16x32_bf16(a[i], b[j], acc[i][j], 0, 0, 0);
    }

    const int nb = n0 >> 7;
    if (nb >= 20) {
        // ---- V: plain bias + scatter ----
        #pragma unroll
        for (int i = 0; i < 4; ++i) {
            int srow[4];
            #pragma unroll
            for (int r = 0; r < 4; ++r) srow[r] = idx[m0 + wm*64 + i*16 + kq*4 + r];
            #pragma unroll
            for (int j = 0; j < 4; ++j) {
                const int o = n0 + wn*64 + j*16 + lm - 2560;
                const float bias = vb[o];
                #pragma unroll
                for (int r = 0; r < 4; ++r)
                    vo[(size_t)srow[r]*512 + o] = (bf16)(acc[i][j][r] + bias);
            }
        }
        return;
    }

    // ---- Q/K head: fused RMSNorm + RoPE ----
    const bool isQ = nb < 16;
    const float* bptr = isQ ? (qb + n0) : (kb + (n0 - 2048));
    const float* wnp  = isQ ? (gen ? qng : qnu) : (gen ? kng : knu);
    bf16* obuf = isQ ? qo : ko;
    const int old_ = isQ ? 2048 : 512;
    const int ocol = (isQ ? nb : nb - 16) * 128;
    const float qs = isQ ? (0.08838834764831845f * 1.4426950408889634f) : 1.0f;
    char* const sXb = (char*)sX;

    // phase 1: pair-pack bf16(acc+bias) into sX[row][d] (even lanes write b32)
    #pragma unroll
    for (int i = 0; i < 4; ++i)
        #pragma unroll
        for (int j = 0; j < 4; ++j) {
            const int d = wn*64 + j*16 + lm;
            const float bias = bptr[d];
            #pragma unroll
            for (int r = 0; r < 4; ++r) {
                bf16 xb = (bf16)(acc[i][j][r] + bias);
                int us = (int)*(unsigned short*)&xb;
                int pp = (us & 0xffff) | (__shfl_xor(us, 1, 64) << 16);
                if (!(lm & 1)) {
                    const int row = wm*64 + i*16 + kq*4 + r;
                    *(unsigned*)(sXb + row*264 + d*2) = (unsigned)pp;
                }
            }
        }
    __syncthreads();

    // phase 2: 2 threads per row (hf = column half), norm + rope + write
    {
        const int row = tid >> 1, hf = tid & 1;
        const int srow = idx[m0 + row];
        const char* rp = sXb + row*264;

        float ss = 0.f;
        #pragma unroll
        for (int c = 0; c < 16; ++c) {
            uint2 u2 = *(const uint2*)(rp + hf*128 + c*8);
            float f0 = bfu_lo(u2.x), f1 = bfu_hi(u2.x);
            float f2 = bfu_lo(u2.y), f3 = bfu_hi(u2.y);
            ss += (f0*f0 + f1*f1) + (f2*f2 + f3*f3);
        }
        ss += __shfl_xor(ss, 1, 64);
        const float rr = rsqrtf(ss * (1.0f/128.0f) + 1e-6f);

        bf16* orow = obuf + (size_t)srow*old_ + ocol + hf*64;
        const float* cz = cosb + (size_t)srow*DH + hf*64;
        const float* sz = sinb + (size_t)srow*DH + hf*64;
        const float sg = hf ? 1.0f : -1.0f;

        #pragma unroll
        for (int c = 0; c < 16; ++c) {
            uint2 m2 = *(const uint2*)(rp + hf*128 + c*8);
            uint2 o2 = *(const uint2*)(rp + (hf^1)*128 + c*8);
            float4 wm4 = *(const float4*)(wnp + hf*64 + c*4);
            float4 wo4 = *(const float4*)(wnp + (hf^1)*64 + c*4);
            float4 c4  = *(const float4*)(cz + c*4);
            float4 s4v = *(const float4*)(sz + c*4);
            float xm0 = bfu_lo(m2.x)*rr, xm1 = bfu_hi(m2.x)*rr;
            float xm2 = bfu_lo(m2.y)*rr, xm3 = bfu_hi(m2.y)*rr;
            float xo0 = bfu_lo(o2.x)*rr, xo1 = bfu_hi(o2.x)*rr;
            float xo2 = bfu_lo(o2.y)*rr, xo3 = bfu_hi(o2.y)*rr;
            float r0 = (xm0*wm4.x*c4.x + sg*xo0*wo4.x*s4v.x) * qs;
            float r1 = (xm1*wm4.y*c4.y + sg*xo1*wo4.y*s4v.y) * qs;
            float r2 = (xm2*wm4.z*c4.z + sg*xo2*wo4.z*s4v.z) * qs;
            float r3 = (xm3*wm4.w*c4.w + sg*xo3*wo4.w*s4v.w) * qs;
            union { bf16 b[4]; ushort4 u; } t;
            t.b[0] = (bf16)r0; t.b[1] = (bf16)r1; t.b[2] = (bf16)r2; t.b[3] = (bf16)r3;
            *(ushort4*)(orow + c*4) = t.u;
        }
    }
}

// ================= 256x256 / BK=64 / 8-phase GEMM core (for k_gemm_out) ==========
#define C0 0
#define C1 16384
#define C2 32768
#define C3 49152

#define STG2(MB, KC, DST)                                                       \
    gl2lds16((MB) + (KC) + go0, (DST) + wave*1024);                             \
    gl2lds16((MB) + (KC) + go1, (DST) + 8192 + wave*1024);

#define PH(RD, MH, DOB, STG, TAIL)                                              \
  {                                                                             \
    _Pragma("unroll")                                                           \
    for (int im = 0; im < 4; ++im)                                              \
        a_[im] = *(const bf16x8*)(sAb + (RD) + (MH)*4096 + im*1024 + abase);    \
    if (DOB) {                                                                  \
        _Pragma("unroll")                                                       \
        for (int jn = 0; jn < 4; ++jn)                                          \
            b_[jn] = *(const bf16x8*)(sBb + (RD) + jn*1024 + bbase);            \
    }                                                                           \
    STG;                                                                        \
    __builtin_amdgcn_s_barrier();                                               \
    __builtin_amdgcn_s_setprio(1);                                              \
    _Pragma("unroll")                                                           \
    for (int im = 0; im < 4; ++im)                                              \
      _Pragma("unroll")                                                         \
      for (int jn = 0; jn < 4; ++jn)                                            \
        acc[(MH)*4+im][jn] = __builtin_amdgcn_mfma_f32_16x16x32_bf16(           \
            a_[im], b_[jn], acc[(MH)*4+im][jn], 0, 0, 0);                       \
    __builtin_amdgcn_s_setprio(0);                                              \
    TAIL;                                                                       \
    __builtin_amdgcn_s_barrier();                                               \
  }

__device__ __forceinline__ void gemm256_core(
    const bf16* __restrict__ A, const bf16* __restrict__ B,
    int m0, int n0, int tid, char* sAb, char* sBb, f32x4 (&acc)[8][4])
{
    const int lane = tid & 63;
    const int lm = lane & 15, kq = lane >> 4;
    const int wave = tid >> 6;
    const int wm = wave >> 2, wn = wave & 3;

    const int swz16 = (kq ^ ((lm >> 1) & 3)) * 16;
    const int abase = wm*8192 + lm*64 + swz16;
    const int bbase = wn*4096 + lm*64 + swz16;

    int go0, go1;
    {
        const int s0 = tid,        r0 = s0 >> 2, c0 = (s0 & 3) ^ ((r0 >> 1) & 3);
        const int s1 = 512 + tid,  r1 = s1 >> 2, c1 = (s1 & 3) ^ ((r1 >> 1) & 3);
        go0 = r0*HID + c0*8;
        go1 = r1*HID + c1*8;
    }
    const bf16* Ab = A + (size_t)m0*HID;
    const bf16* Bb = B + (size_t)n0*HID;

    bf16x8 a_[4], b_[4];

    STG2(Ab, 0,  sAb + C0);  STG2(Ab, 32, sAb + C1);
    STG2(Bb, 0,  sBb + C0);  STG2(Bb, 32, sBb + C1);
    STG2(Ab, 64, sAb + C2);  STG2(Bb, 64, sBb + C2);
    VMCNT(4);
    __builtin_amdgcn_s_barrier();

    #pragma unroll 1
    for (int i = 0; i < 15; ++i) {
        const int kc = 128*i;
        PH(C0, 0, 1, STG2(Ab, kc+96,  sAb+C3), (void)0);
        PH(C0, 1, 0, STG2(Bb, kc+96,  sBb+C3), (void)0);
        PH(C1, 0, 1, STG2(Ab, kc+128, sAb+C0), (void)0);
        PH(C1, 1, 0, STG2(Bb, kc+128, sBb+C0), VMCNT(4));
        PH(C2, 0, 1, STG2(Ab, kc+160, sAb+C1), (void)0);
        PH(C2, 1, 0, STG2(Bb, kc+160, sBb+C1), (void)0);
        PH(C3, 0, 1, STG2(Ab, kc+192, sAb+C2), (void)0);
        PH(C3, 1, 0, STG2(Bb, kc+192, sBb+C2), VMCNT(4));
    }
    {
        PH(C0, 0, 1, STG2(Ab, 2016, sAb+C3), (void)0);
        PH(C0, 1, 0, STG2(Bb, 2016, sBb+C3), (void)0);
        PH(C1, 0, 1, (void)0, (void)0);
        PH(C1, 1, 0, (void)0, VMCNT(0));
        PH(C2, 0, 1, (void)0, (void)0);
        PH(C2, 1, 0, (void)0, (void)0);
        PH(C3, 0, 1, (void)0, (void)0);
        PH(C3, 1, 0, (void)0, (void)0);
    }
}

// ---------------- V transpose: v[s][kvh][d] -> vt[(b*NKV+kvh)*128+d][512] ----------
__global__ __launch_bounds__(256) void k_vtrans(const bf16* __restrict__ v, bf16* __restrict__ vt)
{
    __shared__ __align__(16) bf16 sT[64 * 132];
    const int kvh = blockIdx.y;
    const int s0 = blockIdx.x * 64;
    const int b = s0 >> 9;
    const int pos0 = s0 & 511;
    const int tid = threadIdx.x;

    #pragma unroll
    for (int i = 0; i < 4; ++i) {
        const int c = i*256 + tid;
        const int rowi = c >> 4, col8 = c & 15;
        const uint4 d = *(const uint4*)(v + (size_t)(s0 + rowi)*(NKV*DH) + kvh*DH + col8*8);
        uint2* lp = (uint2*)&sT[rowi*132 + col8*8];
        lp[0] = make_uint2(d.x, d.y);
        lp[1] = make_uint2(d.z, d.w);
    }
    __syncthreads();
    const int dd = tid >> 1, half = tid & 1;
    __align__(16) bf16 tmp[32];
    #pragma unroll
    for (int p = 0; p < 32; ++p) tmp[p] = sT[(half*32 + p)*132 + dd];
    bf16* dst = vt + ((size_t)(b*NKV + kvh)*DH + dd)*LSEQ + pos0 + half*32;
    #pragma unroll
    for (int q = 0; q < 8; ++q) ((ushort4*)dst)[q] = ((ushort4*)tmp)[q];
}

// ---------------- flash attention (causal GQA), bf16 MFMA ------------------------
// Balanced q-tile pairing: block pr handles qt = 7-pr then qt = pr (9 kt-iters).
__global__ __launch_bounds__(256) void k_attn(
    const bf16* __restrict__ qbuf, const bf16* __restrict__ kbuf,
    const bf16* __restrict__ vt, const int* __restrict__ invtyp,
    bf16* __restrict__ aop_u, bf16* __restrict__ aop_g)
{
    __shared__ __align__(16) bf16 sK[2][64*128];   // 32 KB, swizzled
    __shared__ __align__(16) bf16 sV[2][128*64];   // 32 KB, [d][pos] swizzled
    __shared__ __align__(16) bf16 sP[4][16*72];    // 9 KB, stride-72 padded

    const int pr = blockIdx.x;                     // pair index 0..3
    const int h = blockIdx.y, b = blockIdx.z;
    const int kvh = h >> 2;
    const int tid = threadIdx.x, wave = tid >> 6, lane = tid & 63;
    const int lm = lane & 15, kq = lane >> 4;

    const bf16* kbase = kbuf + ((size_t)(b*LSEQ))*(NKV*DH) + kvh*DH;
    const bf16* vbase = vt + ((size_t)(b*NKV + kvh)*DH)*LSEQ;
    bf16* const sPw = &sP[wave][0];

    #pragma unroll 1
    for (int t = 0; t < 2; ++t) {
        const int qt = t ? pr : 7 - pr;
        const int q0 = qt * 64;

        bf16x8 qfrag[4];
        {
            const bf16* qp = qbuf + ((size_t)(b*LSEQ + q0 + wave*16 + lm))*HID + h*DH;
            #pragma unroll
            for (int ks = 0; ks < 4; ++ks)
                qfrag[ks] = *(const bf16x8*)(qp + ks*32 + kq*8);
        }

        f32x4 accO[8] = {};
        float lpart[4] = {0.f, 0.f, 0.f, 0.f};

        if (t) __syncthreads();    // fence LDS reuse from previous tile

        {
            const bf16* kp = kbase;
            const bf16* vp = vbase;
            #pragma unroll
            for (int i = 0; i < 4; ++i) {
                const int g = i*4 + wave;
                const int ch = g*64 + lane;
                { const int row = ch >> 4, cp = ch & 15;
                  const int c = (cp & 8) | ((cp ^ row) & 7);
                  gl2lds16(kp + (size_t)row*(NKV*DH) + c*8, (char*)&sK[0][0] + (size_t)g*1024); }
                { const int d = ch >> 3, cp = ch & 7;
                  const int c = (cp ^ d) & 7;
                  gl2lds16(vp + (size_t)d*LSEQ + c*8, (char*)&sV[0][0] + (size_t)g*1024); }
            }
        }

        for (int kt = 0; kt <= qt; ++kt) {
            const int cur = kt & 1;
            __syncthreads();

            if (kt < qt) {
                const bf16* kp = kbase + (size_t)((kt+1)*64)*(NKV*DH);
                const bf16* vp = vbase + (kt+1)*64;
                const int nxt = cur ^ 1;
                #pragma unroll
                for (int i = 0; i < 4; ++i) {
                    const int g = i*4 + wave;
                    const int ch = g*64 + lane;
                    { const int row = ch >> 4, cp = ch & 15;
                      const int c = (cp & 8) | ((cp ^ row) & 7);
                      gl2lds16(kp + (size_t)row*(NKV*DH) + c*8, (char*)&sK[nxt][0] + (size_t)g*1024); }
                    { const int d = ch >> 3, cp = ch & 7;
                      const int c = (cp ^ d) & 7;
                      gl2lds16(vp + (size_t)d*LSEQ + c*8, (char*)&sV[nxt][0] + (size_t)g*1024); }
                }
            }

            f32x4 s4[4] = {};
            #pragma unroll
            for (int ks = 0; ks < 4; ++ks) {
                const int cq = ks*4 + kq;
                const int cs = (cq & 8) | ((cq ^ lm) & 7);
                #pragma unroll
                for (int nt = 0; nt < 4; ++nt) {
                    bf16x8 bk = *(const bf16x8*)&sK[cur][(nt*16 + lm)*128 + cs*8];
                    s4[nt] = __builtin_amdgcn_mfma_f32_16x16x32_bf16(qfrag[ks], bk, s4[nt], 0, 0, 0);
                }
            }

            const bool diag = (kt == qt);
            #pragma unroll
            for (int r = 0; r < 4; ++r) {
                const int rloc = wave*16 + kq*4 + r;
                float v0 = s4[0][r], v1 = s4[1][r], v2 = s4[2][r], v3 = s4[3][r];
                if (diag) {
                    if (lm      > rloc) v0 = -1e30f;
                    if (lm + 16 > rloc) v1 = -1e30f;
                    if (lm + 32 > rloc) v2 = -1e30f;
                    if (lm + 48 > rloc) v3 = -1e30f;
                }
                const float p0 = exp2f(v0);
                const float p1 = exp2f(v1);
                const float p2 = exp2f(v2);
                const float p3 = exp2f(v3);
                lpart[r] += (p0 + p1) + (p2 + p3);
                const int prow = (kq*4 + r) * 72;
                sPw[prow + lm]      = (bf16)p0;
                sPw[prow + 16 + lm] = (bf16)p1;
                sPw[prow + 32 + lm] = (bf16)p2;
                sPw[prow + 48 + lm] = (bf16)p3;
            }

            #pragma unroll
            for (int pc = 0; pc < 2; ++pc) {
                bf16x8 ap = *(const bf16x8*)&sPw[lm*72 + pc*32 + kq*8];
                #pragma unroll
                for (int dt = 0; dt < 8; ++dt) {
                    const int cv = (pc*4 + kq);
                    const int cs = (cv ^ lm) & 7;
                    bf16x8 bv = *(const bf16x8*)&sV[cur][(dt*16 + lm)*64 + cs*8];
                    accO[dt] = __builtin_amdgcn_mfma_f32_16x16x32_bf16(ap, bv, accO[dt], 0, 0, 0);
                }
            }
        }

        #pragma unroll
        for (int r = 0; r < 4; ++r) {
            float l = lpart[r];
            l += __shfl_xor(l, 1, 64);
            l += __shfl_xor(l, 2, 64);
            l += __shfl_xor(l, 4, 64);
            l += __shfl_xor(l, 8, 64);
            const int srow = b*LSEQ + q0 + wave*16 + kq*4 + r;
            const int code = invtyp[srow];
            bf16* dst = (code & 1) ? aop_g : aop_u;
            const size_t off = (size_t)(code >> 1)*HID + h*DH;
            const float inv_l = 1.0f / l;
            #pragma unroll
            for (int dt = 0; dt < 8; ++dt)
                dst[off + dt*16 + lm] = (bf16)(accO[dt][r] * inv_l);
        }
    }
}

// ---------------- Output GEMM (256^2 8-phase, XCD-swizzled 1-D grid) -------------
__global__ __launch_bounds__(512, 2) void k_gemm_out(
    const bf16* __restrict__ Au, const bf16* __restrict__ Ag,
    const bf16* __restrict__ Wu, const bf16* __restrict__ Wg,
    float* __restrict__ out)
{
    __shared__ __align__(16) bf16 sA[4][256*32];
    __shared__ __align__(16) bf16 sB[4][256*32];

    const int lin = blockIdx.x;
    const int idx = (lin & 7) * 32 + (lin >> 3);
    const int gen = idx / 128;
    const int rem = idx - gen * 128;
    const int my  = rem >> 3;
    const int nx_ = rem & 7;
    const int m0 = my * 256, n0 = nx_ * 256;

    const bf16* A = gen ? Ag : Au;
    const bf16* W = gen ? Wg : Wu;
    float* O = out + (size_t)gen * HALF * HID;

    const int tid = threadIdx.x;
    const int wave = tid >> 6, lane = tid & 63;
    const int lm = lane & 15, kq = lane >> 4;
    const int wm = wave >> 2, wn = wave & 3;

    f32x4 acc[8][4] = {};
    gemm256_core(A, W, m0, n0, tid, (char*)&sA[0][0], (char*)&sB[0][0], acc);

    #pragma unroll
    for (int im = 0; im < 8; ++im)
        #pragma unroll
        for (int jn = 0; jn < 4; ++jn)
            #pragma unroll
            for (int r = 0; r < 4; ++r)
                O[(size_t)(m0 + wm*128 + im*16 + kq*4 + r)*HID + (n0 + wn*64 + jn*16 + lm)]
                    = acc[im][jn][r];
}

extern "C" void kernel_launch(void* const* d_in, const int* in_sizes, int n_in,
                              void* d_out, int out_size, void* d_ws, size_t ws_size,
                              hipStream_t stream)
{
    (void)in_sizes; (void)n_in; (void)out_size; (void)ws_size;
    const float* x_u  = (const float*)d_in[0];
    const float* x_g  = (const float*)d_in[1];
    const int*   ui   = (const int*)d_in[2];
    const int*   gi   = (const int*)d_in[3];
    const float* q_w  = (const float*)d_in[4];
    const float* q_b  = (const float*)d_in[5];
    const float* k_w  = (const float*)d_in[6];
    const float* k_b  = (const float*)d_in[7];
    const float* v_w  = (const float*)d_in[8];
    const float* v_b  = (const float*)d_in[9];
    const float* o_w  = (const float*)d_in[10];
    const float* q_wg = (const float*)d_in[11];
    const float* q_bg = (const float*)d_in[12];
    const float* k_wg = (const float*)d_in[13];
    const float* k_bg = (const float*)d_in[14];
    const float* v_wg = (const float*)d_in[15];
    const float* v_bg = (const float*)d_in[16];
    const float* o_wg = (const float*)d_in[17];
    const float* qn_u = (const float*)d_in[18];
    const float* kn_u = (const float*)d_in[19];
    const float* qn_g = (const float*)d_in[20];
    const float* kn_g = (const float*)d_in[21];
    const float* cosb = (const float*)d_in[22];
    const float* sinb = (const float*)d_in[23];

    char* w = (char*)d_ws;
    auto alloc = [&](size_t bytes) { char* p = w; w += (bytes + 255) & ~(size_t)255; return p; };
    bf16* xb_u   = (bf16*)alloc((size_t)HALF*HID*2);
    bf16* xb_g   = (bf16*)alloc((size_t)HALF*HID*2);
    bf16* wqkv_u = (bf16*)alloc((size_t)3072*HID*2);
    bf16* wqkv_g = (bf16*)alloc((size_t)3072*HID*2);
    bf16* wo_u   = (bf16*)alloc((size_t)HID*HID*2);
    bf16* wo_g   = (bf16*)alloc((size_t)HID*HID*2);
    bf16* qbuf   = (bf16*)alloc((size_t)S_TOT*HID*2);
    bf16* kbuf   = (bf16*)alloc((size_t)S_TOT*NKV*DH*2);
    bf16* vbuf   = (bf16*)alloc((size_t)S_TOT*NKV*DH*2);
    bf16* vtb    = (bf16*)alloc((size_t)S_TOT*NKV*DH*2);
    int*  invtyp = (int*)alloc((size_t)S_TOT*4);
    bf16* aop_u = xb_u;     // attention output aliases dead xb
    bf16* aop_g = xb_g;

    CvtArgs ca;
    int si = 0;
    auto seg = [&](const float* s, bf16* d, size_t n) {
        ca.src[si] = s; ca.dst[si] = d; ca.n4[si] = (int)(n / 4); ++si;
    };
    seg(x_u,  xb_u,                (size_t)HALF*HID);
    seg(x_g,  xb_g,                (size_t)HALF*HID);
    seg(q_w,  wqkv_u,              (size_t)2048*HID);
    seg(k_w,  wqkv_u + 2048*HID,   (size_t)512*HID);
    seg(v_w,  wqkv_u + 2560*HID,   (size_t)512*HID);
    seg(q_wg, wqkv_g,              (size_t)2048*HID);
    seg(k_wg, wqkv_g + 2048*HID,   (size_t)512*HID);
    seg(v_wg, wqkv_g + 2560*HID,   (size_t)512*HID);
    seg(o_w,  wo_u,                (size_t)HID*HID);
    seg(o_wg, wo_g,                (size_t)HID*HID);
    k_convert_seg<<<36880, 256, 0, stream>>>(ca, ui, gi, invtyp);

    k_gemm_qkv<<<dim3(24, 32, 2), 256, 0, stream>>>(
        xb_u, xb_g, wqkv_u, wqkv_g,
        q_b, k_b, v_b, q_bg, k_bg, v_bg,
        ui, gi, qn_u, qn_g, kn_u, kn_g, cosb, sinb,
        qbuf, kbuf, vbuf);

    k_vtrans<<<dim3(S_TOT/64, NKV), 256, 0, stream>>>(vbuf, vtb);

    k_attn<<<dim3(4, NH, 16), 256, 0, stream>>>(
        qbuf, kbuf, vtb, invtyp, aop_u, aop_g);

    k_gemm_out<<<dim3(256), 512, 0, stream>>>(
        aop_u, aop_g, wo_u, wo_g, (float*)d_out);
}

// Round 6
// 498.242 us; speedup vs baseline: 1.0575x; 1.0575x over previous
//
#include <hip/hip_runtime.h>

typedef __bf16 bf16;
typedef __bf16 bf16x8 __attribute__((ext_vector_type(8)));
typedef float  f32x4  __attribute__((ext_vector_type(4)));

#define HALF   4096
#define S_TOT  8192
#define HID    2048
#define NH     16
#define NKV    4
#define DH     128
#define LSEQ   512

typedef const __attribute__((address_space(1))) void* as1_cvp;
typedef __attribute__((address_space(3))) void* as3_vp;

__device__ __forceinline__ void gl2lds16(const void* g, void* l) {
    // HW semantics: lane i's 16B lands at (wave-uniform) l + i*16
    __builtin_amdgcn_global_load_lds((as1_cvp)g, (as3_vp)l, 16, 0, 0);
}

#define VMCNT(n) asm volatile("s_waitcnt vmcnt(" #n ")" ::: "memory")

// ---------------- fp32 -> bf16 convert (+ invtyp tail blocks) --------------------
struct CvtArgs {
    const float* src[10];
    bf16*        dst[10];
    int          n4[10];
};
__global__ __launch_bounds__(256) void k_convert_seg(CvtArgs a,
    const int* __restrict__ ui, const int* __restrict__ gi, int* __restrict__ it) {
    int rem = blockIdx.x;
    if (rem >= 36864) {            // invtyp tail: invtyp[s] = packed_row*2 | is_gen
        int t = (rem - 36864) * 256 + threadIdx.x;
        if (t < HALF) { it[ui[t]] = t << 1; it[gi[t]] = (t << 1) | 1; }
        return;
    }
    const float* src; bf16* dst;
    if      (rem < 8192)           { src=a.src[0]; dst=a.dst[0]; }
    else if ((rem -= 8192) < 8192) { src=a.src[1]; dst=a.dst[1]; }
    else if ((rem -= 8192) < 4096) { src=a.src[2]; dst=a.dst[2]; }
    else if ((rem -= 4096) < 1024) { src=a.src[3]; dst=a.dst[3]; }
    else if ((rem -= 1024) < 1024) { src=a.src[4]; dst=a.dst[4]; }
    else if ((rem -= 1024) < 4096) { src=a.src[5]; dst=a.dst[5]; }
    else if ((rem -= 4096) < 1024) { src=a.src[6]; dst=a.dst[6]; }
    else if ((rem -= 1024) < 1024) { src=a.src[7]; dst=a.dst[7]; }
    else if ((rem -= 1024) < 4096) { src=a.src[8]; dst=a.dst[8]; }
    else    { rem -= 4096;           src=a.src[9]; dst=a.dst[9]; }
    const int i = (rem << 8) + threadIdx.x;
    float4 v = ((const float4*)src)[i];
    union { bf16 b[4]; ushort4 u; } t;
    t.b[0] = (bf16)v.x; t.b[1] = (bf16)v.y; t.b[2] = (bf16)v.z; t.b[3] = (bf16)v.w;
    ((ushort4*)dst)[i] = t.u;
}

// ---------------- QKV GEMM (R0-best 128^2/BK32 core, XCD-swizzled grid) ----------
__global__ __launch_bounds__(256) void k_gemm_qkv(
    const bf16* __restrict__ Xu, const bf16* __restrict__ Xg,
    const bf16* __restrict__ Wu, const bf16* __restrict__ Wg,
    const float* __restrict__ qbu, const float* __restrict__ kbu, const float* __restrict__ vbu,
    const float* __restrict__ qbg, const float* __restrict__ kbg, const float* __restrict__ vbg,
    const int* __restrict__ ui, const int* __restrict__ gi,
    bf16* __restrict__ qo, bf16* __restrict__ ko, bf16* __restrict__ vo)
{
    // XCD-chunked bijective swizzle: 1536 = 8 XCDs x 192; n-fastest in chunk
    const int lin = blockIdx.x;
    const int idx2 = (lin & 7) * 192 + (lin >> 3);
    const int gen = idx2 / 768;
    const int rem = idx2 - gen * 768;
    const int my  = rem / 24;
    const int nx  = rem - my * 24;
    const int m0 = my * 128, n0 = nx * 128;

    const bf16* X = gen ? Xg : Xu;
    const bf16* W = gen ? Wg : Wu;
    const float* qb = gen ? qbg : qbu;
    const float* kb = gen ? kbg : kbu;
    const float* vb = gen ? vbg : vbu;
    const int* idx = gen ? gi : ui;

    __shared__ __align__(16) bf16 sA[128*32];
    __shared__ __align__(16) bf16 sB[128*32];

    const int tid = threadIdx.x;
    const int wave = tid >> 6, lane = tid & 63;
    const int lm = lane & 15, kq = lane >> 4;
    const int wm = wave >> 1, wn = wave & 1;

    f32x4 acc[4][4] = {};

    for (int k0 = 0; k0 < HID; k0 += 32) {
        __syncthreads();
        #pragma unroll
        for (int i = 0; i < 2; ++i) {
            const int g = i*4 + wave;
            const int c = g*64 + lane;
            const int row = c >> 2, col = c & 3;
            gl2lds16(X + (size_t)(m0+row)*HID + k0 + col*8, (char*)sA + (size_t)g*1024);
            gl2lds16(W + (size_t)(n0+row)*HID + k0 + col*8, (char*)sB + (size_t)g*1024);
        }
        __syncthreads();
        bf16x8 a[4], b[4];
        #pragma unroll
        for (int i = 0; i < 4; ++i) a[i] = *(const bf16x8*)&sA[(wm*64 + i*16 + lm)*32 + kq*8];
        #pragma unroll
        for (int j = 0; j < 4; ++j) b[j] = *(const bf16x8*)&sB[(wn*64 + j*16 + lm)*32 + kq*8];
        #pragma unroll
        for (int i = 0; i < 4; ++i)
            #pragma unroll
            for (int j = 0; j < 4; ++j)
                acc[i][j] = __builtin_amdgcn_mfma_f32_16x16x32_bf16(a[i], b[j], acc[i][j], 0, 0, 0);
    }

    #pragma unroll
    for (int i = 0; i < 4; ++i) {
        int srow[4];
        #pragma unroll
        for (int r = 0; r < 4; ++r) srow[r] = idx[m0 + wm*64 + i*16 + kq*4 + r];
        #pragma unroll
        for (int j = 0; j < 4; ++j) {
            const int o = n0 + wn*64 + j*16 + lm;
            bf16* dst; float bias; int off0, ld;
            if (o < 2048)      { dst = qo; ld = 2048; off0 = o;        bias = qb[o]; }
            else if (o < 2560) { dst = ko; ld = 512;  off0 = o - 2048; bias = kb[o-2048]; }
            else               { dst = vo; ld = 512;  off0 = o - 2560; bias = vb[o-2560]; }
            #pragma unroll
            for (int r = 0; r < 4; ++r)
                dst[(size_t)srow[r]*ld + off0] = (bf16)(acc[i][j][r] + bias);
        }
    }
}

// ================= 256x256 / BK=64 / 8-phase GEMM core (for k_gemm_out) ==========
#define C0 0
#define C1 16384
#define C2 32768
#define C3 49152

#define STG2(MB, KC, DST)                                                       \
    gl2lds16((MB) + (KC) + go0, (DST) + wave*1024);                             \
    gl2lds16((MB) + (KC) + go1, (DST) + 8192 + wave*1024);

#define PH(RD, MH, DOB, STG, TAIL)                                              \
  {                                                                             \
    _Pragma("unroll")                                                           \
    for (int im = 0; im < 4; ++im)                                              \
        a_[im] = *(const bf16x8*)(sAb + (RD) + (MH)*4096 + im*1024 + abase);    \
    if (DOB) {                                                                  \
        _Pragma("unroll")                                                       \
        for (int jn = 0; jn < 4; ++jn)                                          \
            b_[jn] = *(const bf16x8*)(sBb + (RD) + jn*1024 + bbase);            \
    }                                                                           \
    STG;                                                                        \
    __builtin_amdgcn_s_barrier();                                               \
    __builtin_amdgcn_s_setprio(1);                                              \
    _Pragma("unroll")                                                           \
    for (int im = 0; im < 4; ++im)                                              \
      _Pragma("unroll")                                                         \
      for (int jn = 0; jn < 4; ++jn)                                            \
        acc[(MH)*4+im][jn] = __builtin_amdgcn_mfma_f32_16x16x32_bf16(           \
            a_[im], b_[jn], acc[(MH)*4+im][jn], 0, 0, 0);                       \
    __builtin_amdgcn_s_setprio(0);                                              \
    TAIL;                                                                       \
    __builtin_amdgcn_s_barrier();                                               \
  }

__device__ __forceinline__ void gemm256_core(
    const bf16* __restrict__ A, const bf16* __restrict__ B,
    int m0, int n0, int tid, char* sAb, char* sBb, f32x4 (&acc)[8][4])
{
    const int lane = tid & 63;
    const int lm = lane & 15, kq = lane >> 4;
    const int wave = tid >> 6;
    const int wm = wave >> 2, wn = wave & 3;

    const int swz16 = (kq ^ ((lm >> 1) & 3)) * 16;
    const int abase = wm*8192 + lm*64 + swz16;
    const int bbase = wn*4096 + lm*64 + swz16;

    int go0, go1;
    {
        const int s0 = tid,        r0 = s0 >> 2, c0 = (s0 & 3) ^ ((r0 >> 1) & 3);
        const int s1 = 512 + tid,  r1 = s1 >> 2, c1 = (s1 & 3) ^ ((r1 >> 1) & 3);
        go0 = r0*HID + c0*8;
        go1 = r1*HID + c1*8;
    }
    const bf16* Ab = A + (size_t)m0*HID;
    const bf16* Bb = B + (size_t)n0*HID;

    bf16x8 a_[4], b_[4];

    STG2(Ab, 0,  sAb + C0);  STG2(Ab, 32, sAb + C1);
    STG2(Bb, 0,  sBb + C0);  STG2(Bb, 32, sBb + C1);
    STG2(Ab, 64, sAb + C2);  STG2(Bb, 64, sBb + C2);
    VMCNT(4);
    __builtin_amdgcn_s_barrier();

    #pragma unroll 1
    for (int i = 0; i < 15; ++i) {
        const int kc = 128*i;
        PH(C0, 0, 1, STG2(Ab, kc+96,  sAb+C3), (void)0);
        PH(C0, 1, 0, STG2(Bb, kc+96,  sBb+C3), (void)0);
        PH(C1, 0, 1, STG2(Ab, kc+128, sAb+C0), (void)0);
        PH(C1, 1, 0, STG2(Bb, kc+128, sBb+C0), VMCNT(4));
        PH(C2, 0, 1, STG2(Ab, kc+160, sAb+C1), (void)0);
        PH(C2, 1, 0, STG2(Bb, kc+160, sBb+C1), (void)0);
        PH(C3, 0, 1, STG2(Ab, kc+192, sAb+C2), (void)0);
        PH(C3, 1, 0, STG2(Bb, kc+192, sBb+C2), VMCNT(4));
    }
    {
        PH(C0, 0, 1, STG2(Ab, 2016, sAb+C3), (void)0);
        PH(C0, 1, 0, STG2(Bb, 2016, sBb+C3), (void)0);
        PH(C1, 0, 1, (void)0, (void)0);
        PH(C1, 1, 0, (void)0, VMCNT(0));
        PH(C2, 0, 1, (void)0, (void)0);
        PH(C2, 1, 0, (void)0, (void)0);
        PH(C3, 0, 1, (void)0, (void)0);
        PH(C3, 1, 0, (void)0, (void)0);
    }
}

// ---------------- fused post: RMSNorm+RoPE (blocks 0..40959) + V transpose -------
// Norm part: one wave per 128-row, in place on qbuf/kbuf; Q rows scaled by
// 1/sqrt(D)*log2(e) so attention softmax is pure exp2.
// Vtrans part (blocks 40960..41471): v[s][kvh][d] -> vt[(b*NKV+kvh)*128+d][512].
__global__ __launch_bounds__(256) void k_post(
    bf16* __restrict__ qbuf, bf16* __restrict__ kbuf,
    const bf16* __restrict__ v, bf16* __restrict__ vt,
    const float* __restrict__ cosb, const float* __restrict__ sinb,
    const int* __restrict__ invtyp,
    const float* __restrict__ qnu, const float* __restrict__ qng,
    const float* __restrict__ knu, const float* __restrict__ kng)
{
    __shared__ __align__(16) bf16 sT[64 * 132];
    const int bx = blockIdx.x;
    const int tid = threadIdx.x;

    if (bx < 40960) {
        const int row = bx * 4 + (tid >> 6);
        const int lane = tid & 63;
        const int s = row / (NH + NKV), hh = row % (NH + NKV);
        const int isg = invtyp[s] & 1;
        bf16* ptr; const float* w; float qs;
        if (hh < NH) { ptr = qbuf + (size_t)s*HID + hh*DH;           w = isg ? qng : qnu;
                       qs = 0.08838834764831845f * 1.4426950408889634f; }
        else         { ptr = kbuf + (size_t)s*(NKV*DH) + (hh-NH)*DH; w = isg ? kng : knu;
                       qs = 1.0f; }

        const unsigned u = *(const unsigned*)((const unsigned short*)ptr + 2*lane);
        const float f0 = __uint_as_float(u << 16);
        const float f1 = __uint_as_float(u & 0xffff0000u);
        float ss = f0*f0 + f1*f1;
        #pragma unroll
        for (int m = 32; m; m >>= 1) ss += __shfl_xor(ss, m, 64);
        const float r = rsqrtf(ss * (1.0f/128.0f) + 1e-6f);
        const float2 wv = *(const float2*)(w + 2*lane);
        const float xn0 = f0 * r * wv.x;
        const float xn1 = f1 * r * wv.y;
        const float po0 = __shfl_xor(xn0, 32, 64);
        const float po1 = __shfl_xor(xn1, 32, 64);
        const float2 c2 = *(const float2*)(cosb + (size_t)s*DH + 2*lane);
        const float2 s2 = *(const float2*)(sinb + (size_t)s*DH + 2*lane);
        const float sg = (lane < 32) ? -1.0f : 1.0f;
        const float o0 = (xn0 * c2.x + sg * po0 * s2.x) * qs;
        const float o1 = (xn1 * c2.y + sg * po1 * s2.y) * qs;
        union { unsigned short us[2]; unsigned u; } t;
        bf16 b0 = (bf16)o0, b1 = (bf16)o1;
        t.us[0] = *(unsigned short*)&b0; t.us[1] = *(unsigned short*)&b1;
        *(unsigned*)((unsigned short*)ptr + 2*lane) = t.u;
        return;
    }

    // ---- V transpose ----
    const int vb = bx - 40960;          // 0..511
    const int kvh = vb & 3;
    const int s0 = (vb >> 2) * 64;
    const int b = s0 >> 9;
    const int pos0 = s0 & 511;

    #pragma unroll
    for (int i = 0; i < 4; ++i) {
        const int c = i*256 + tid;
        const int rowi = c >> 4, col8 = c & 15;
        const uint4 d = *(const uint4*)(v + (size_t)(s0 + rowi)*(NKV*DH) + kvh*DH + col8*8);
        uint2* lp = (uint2*)&sT[rowi*132 + col8*8];
        lp[0] = make_uint2(d.x, d.y);
        lp[1] = make_uint2(d.z, d.w);
    }
    __syncthreads();
    const int dd = tid >> 1, half = tid & 1;
    __align__(16) bf16 tmp[32];
    #pragma unroll
    for (int p = 0; p < 32; ++p) tmp[p] = sT[(half*32 + p)*132 + dd];
    bf16* dst = vt + ((size_t)(b*NKV + kvh)*DH + dd)*LSEQ + pos0 + half*32;
    #pragma unroll
    for (int q = 0; q < 8; ++q) ((ushort4*)dst)[q] = ((ushort4*)tmp)[q];
}

// ---------------- flash attention (causal GQA), bf16 MFMA ------------------------
// Balanced q-tile pairing: block pr handles qt = 7-pr then qt = pr (9 kt-iters).
__global__ __launch_bounds__(256) void k_attn(
    const bf16* __restrict__ qbuf, const bf16* __restrict__ kbuf,
    const bf16* __restrict__ vt, const int* __restrict__ invtyp,
    bf16* __restrict__ aop_u, bf16* __restrict__ aop_g)
{
    __shared__ __align__(16) bf16 sK[2][64*128];   // 32 KB, swizzled
    __shared__ __align__(16) bf16 sV[2][128*64];   // 32 KB, [d][pos] swizzled
    __shared__ __align__(16) bf16 sP[4][16*72];    // 9 KB, stride-72 padded

    const int pr = blockIdx.x;                     // pair index 0..3
    const int h = blockIdx.y, b = blockIdx.z;
    const int kvh = h >> 2;
    const int tid = threadIdx.x, wave = tid >> 6, lane = tid & 63;
    const int lm = lane & 15, kq = lane >> 4;

    const bf16* kbase = kbuf + ((size_t)(b*LSEQ))*(NKV*DH) + kvh*DH;
    const bf16* vbase = vt + ((size_t)(b*NKV + kvh)*DH)*LSEQ;
    bf16* const sPw = &sP[wave][0];

    #pragma unroll 1
    for (int t = 0; t < 2; ++t) {
        const int qt = t ? pr : 7 - pr;
        const int q0 = qt * 64;

        bf16x8 qfrag[4];
        {
            const bf16* qp = qbuf + ((size_t)(b*LSEQ + q0 + wave*16 + lm))*HID + h*DH;
            #pragma unroll
            for (int ks = 0; ks < 4; ++ks)
                qfrag[ks] = *(const bf16x8*)(qp + ks*32 + kq*8);
        }

        f32x4 accO[8] = {};
        float lpart[4] = {0.f, 0.f, 0.f, 0.f};

        if (t) __syncthreads();    // fence LDS reuse from previous tile

        {
            const bf16* kp = kbase;
            const bf16* vp = vbase;
            #pragma unroll
            for (int i = 0; i < 4; ++i) {
                const int g = i*4 + wave;
                const int ch = g*64 + lane;
                { const int row = ch >> 4, cp = ch & 15;
                  const int c = (cp & 8) | ((cp ^ row) & 7);
                  gl2lds16(kp + (size_t)row*(NKV*DH) + c*8, (char*)&sK[0][0] + (size_t)g*1024); }
                { const int d = ch >> 3, cp = ch & 7;
                  const int c = (cp ^ d) & 7;
                  gl2lds16(vp + (size_t)d*LSEQ + c*8, (char*)&sV[0][0] + (size_t)g*1024); }
            }
        }

        for (int kt = 0; kt <= qt; ++kt) {
            const int cur = kt & 1;
            __syncthreads();

            if (kt < qt) {
                const bf16* kp = kbase + (size_t)((kt+1)*64)*(NKV*DH);
                const bf16* vp = vbase + (kt+1)*64;
                const int nxt = cur ^ 1;
                #pragma unroll
                for (int i = 0; i < 4; ++i) {
                    const int g = i*4 + wave;
                    const int ch = g*64 + lane;
                    { const int row = ch >> 4, cp = ch & 15;
                      const int c = (cp & 8) | ((cp ^ row) & 7);
                      gl2lds16(kp + (size_t)row*(NKV*DH) + c*8, (char*)&sK[nxt][0] + (size_t)g*1024); }
                    { const int d = ch >> 3, cp = ch & 7;
                      const int c = (cp ^ d) & 7;
                      gl2lds16(vp + (size_t)d*LSEQ + c*8, (char*)&sV[nxt][0] + (size_t)g*1024); }
                }
            }

            f32x4 s4[4] = {};
            #pragma unroll
            for (int ks = 0; ks < 4; ++ks) {
                const int cq = ks*4 + kq;
                const int cs = (cq & 8) | ((cq ^ lm) & 7);
                #pragma unroll
                for (int nt = 0; nt < 4; ++nt) {
                    bf16x8 bk = *(const bf16x8*)&sK[cur][(nt*16 + lm)*128 + cs*8];
                    s4[nt] = __builtin_amdgcn_mfma_f32_16x16x32_bf16(qfrag[ks], bk, s4[nt], 0, 0, 0);
                }
            }

            const bool diag = (kt == qt);
            #pragma unroll
            for (int r = 0; r < 4; ++r) {
                const int rloc = wave*16 + kq*4 + r;
                float v0 = s4[0][r], v1 = s4[1][r], v2 = s4[2][r], v3 = s4[3][r];
                if (diag) {
                    if (lm      > rloc) v0 = -1e30f;
                    if (lm + 16 > rloc) v1 = -1e30f;
                    if (lm + 32 > rloc) v2 = -1e30f;
                    if (lm + 48 > rloc) v3 = -1e30f;
                }
                const float p0 = exp2f(v0);
                const float p1 = exp2f(v1);
                const float p2 = exp2f(v2);
                const float p3 = exp2f(v3);
                lpart[r] += (p0 + p1) + (p2 + p3);
                const int prow = (kq*4 + r) * 72;
                sPw[prow + lm]      = (bf16)p0;
                sPw[prow + 16 + lm] = (bf16)p1;
                sPw[prow + 32 + lm] = (bf16)p2;
                sPw[prow + 48 + lm] = (bf16)p3;
            }

            #pragma unroll
            for (int pc = 0; pc < 2; ++pc) {
                bf16x8 ap = *(const bf16x8*)&sPw[lm*72 + pc*32 + kq*8];
                #pragma unroll
                for (int dt = 0; dt < 8; ++dt) {
                    const int cv = (pc*4 + kq);
                    const int cs = (cv ^ lm) & 7;
                    bf16x8 bv = *(const bf16x8*)&sV[cur][(dt*16 + lm)*64 + cs*8];
                    accO[dt] = __builtin_amdgcn_mfma_f32_16x16x32_bf16(ap, bv, accO[dt], 0, 0, 0);
                }
            }
        }

        #pragma unroll
        for (int r = 0; r < 4; ++r) {
            float l = lpart[r];
            l += __shfl_xor(l, 1, 64);
            l += __shfl_xor(l, 2, 64);
            l += __shfl_xor(l, 4, 64);
            l += __shfl_xor(l, 8, 64);
            const int srow = b*LSEQ + q0 + wave*16 + kq*4 + r;
            const int code = invtyp[srow];
            bf16* dst = (code & 1) ? aop_g : aop_u;
            const size_t off = (size_t)(code >> 1)*HID + h*DH;
            const float inv_l = 1.0f / l;
            #pragma unroll
            for (int dt = 0; dt < 8; ++dt)
                dst[off + dt*16 + lm] = (bf16)(accO[dt][r] * inv_l);
        }
    }
}

// ---------------- Output GEMM (256^2 8-phase, XCD-swizzled 1-D grid) -------------
__global__ __launch_bounds__(512, 2) void k_gemm_out(
    const bf16* __restrict__ Au, const bf16* __restrict__ Ag,
    const bf16* __restrict__ Wu, const bf16* __restrict__ Wg,
    float* __restrict__ out)
{
    __shared__ __align__(16) bf16 sA[4][256*32];
    __shared__ __align__(16) bf16 sB[4][256*32];

    const int lin = blockIdx.x;
    const int idx = (lin & 7) * 32 + (lin >> 3);
    const int gen = idx / 128;
    const int rem = idx - gen * 128;
    const int my  = rem >> 3;
    const int nx_ = rem & 7;
    const int m0 = my * 256, n0 = nx_ * 256;

    const bf16* A = gen ? Ag : Au;
    const bf16* W = gen ? Wg : Wu;
    float* O = out + (size_t)gen * HALF * HID;

    const int tid = threadIdx.x;
    const int wave = tid >> 6, lane = tid & 63;
    const int lm = lane & 15, kq = lane >> 4;
    const int wm = wave >> 2, wn = wave & 3;

    f32x4 acc[8][4] = {};
    gemm256_core(A, W, m0, n0, tid, (char*)&sA[0][0], (char*)&sB[0][0], acc);

    #pragma unroll
    for (int im = 0; im < 8; ++im)
        #pragma unroll
        for (int jn = 0; jn < 4; ++jn)
            #pragma unroll
            for (int r = 0; r < 4; ++r)
                O[(size_t)(m0 + wm*128 + im*16 + kq*4 + r)*HID + (n0 + wn*64 + jn*16 + lm)]
                    = acc[im][jn][r];
}

extern "C" void kernel_launch(void* const* d_in, const int* in_sizes, int n_in,
                              void* d_out, int out_size, void* d_ws, size_t ws_size,
                              hipStream_t stream)
{
    (void)in_sizes; (void)n_in; (void)out_size; (void)ws_size;
    const float* x_u  = (const float*)d_in[0];
    const float* x_g  = (const float*)d_in[1];
    const int*   ui   = (const int*)d_in[2];
    const int*   gi   = (const int*)d_in[3];
    const float* q_w  = (const float*)d_in[4];
    const float* q_b  = (const float*)d_in[5];
    const float* k_w  = (const float*)d_in[6];
    const float* k_b  = (const float*)d_in[7];
    const float* v_w  = (const float*)d_in[8];
    const float* v_b  = (const float*)d_in[9];
    const float* o_w  = (const float*)d_in[10];
    const float* q_wg = (const float*)d_in[11];
    const float* q_bg = (const float*)d_in[12];
    const float* k_wg = (const float*)d_in[13];
    const float* k_bg = (const float*)d_in[14];
    const float* v_wg = (const float*)d_in[15];
    const float* v_bg = (const float*)d_in[16];
    const float* o_wg = (const float*)d_in[17];
    const float* qn_u = (const float*)d_in[18];
    const float* kn_u = (const float*)d_in[19];
    const float* qn_g = (const float*)d_in[20];
    const float* kn_g = (const float*)d_in[21];
    const float* cosb = (const float*)d_in[22];
    const float* sinb = (const float*)d_in[23];

    char* w = (char*)d_ws;
    auto alloc = [&](size_t bytes) { char* p = w; w += (bytes + 255) & ~(size_t)255; return p; };
    bf16* xb_u   = (bf16*)alloc((size_t)HALF*HID*2);
    bf16* xb_g   = (bf16*)alloc((size_t)HALF*HID*2);
    bf16* wqkv_u = (bf16*)alloc((size_t)3072*HID*2);
    bf16* wqkv_g = (bf16*)alloc((size_t)3072*HID*2);
    bf16* wo_u   = (bf16*)alloc((size_t)HID*HID*2);
    bf16* wo_g   = (bf16*)alloc((size_t)HID*HID*2);
    bf16* qbuf   = (bf16*)alloc((size_t)S_TOT*HID*2);
    bf16* kbuf   = (bf16*)alloc((size_t)S_TOT*NKV*DH*2);
    bf16* vbuf   = (bf16*)alloc((size_t)S_TOT*NKV*DH*2);
    bf16* vtb    = (bf16*)alloc((size_t)S_TOT*NKV*DH*2);
    int*  invtyp = (int*)alloc((size_t)S_TOT*4);
    bf16* aop_u = xb_u;     // attention output aliases dead xb
    bf16* aop_g = xb_g;

    CvtArgs ca;
    int si = 0;
    auto seg = [&](const float* s, bf16* d, size_t n) {
        ca.src[si] = s; ca.dst[si] = d; ca.n4[si] = (int)(n / 4); ++si;
    };
    seg(x_u,  xb_u,                (size_t)HALF*HID);
    seg(x_g,  xb_g,                (size_t)HALF*HID);
    seg(q_w,  wqkv_u,              (size_t)2048*HID);
    seg(k_w,  wqkv_u + 2048*HID,   (size_t)512*HID);
    seg(v_w,  wqkv_u + 2560*HID,   (size_t)512*HID);
    seg(q_wg, wqkv_g,              (size_t)2048*HID);
    seg(k_wg, wqkv_g + 2048*HID,   (size_t)512*HID);
    seg(v_wg, wqkv_g + 2560*HID,   (size_t)512*HID);
    seg(o_w,  wo_u,                (size_t)HID*HID);
    seg(o_wg, wo_g,                (size_t)HID*HID);
    k_convert_seg<<<36880, 256, 0, stream>>>(ca, ui, gi, invtyp);

    k_gemm_qkv<<<dim3(1536), 256, 0, stream>>>(
        xb_u, xb_g, wqkv_u, wqkv_g,
        q_b, k_b, v_b, q_bg, k_bg, v_bg,
        ui, gi, qbuf, kbuf, vbuf);

    k_post<<<41472, 256, 0, stream>>>(
        qbuf, kbuf, vbuf, vtb, cosb, sinb, invtyp,
        qn_u, qn_g, kn_u, kn_g);

    k_attn<<<dim3(4, NH, 16), 256, 0, stream>>>(
        qbuf, kbuf, vtb, invtyp, aop_u, aop_g);

    k_gemm_out<<<dim3(256), 512, 0, stream>>>(
        aop_u, aop_g, wo_u, wo_g, (float*)d_out);
}